// Round 2
// baseline (2253.130 us; speedup 1.0000x reference)
//
#include <hip/hip_runtime.h>
#include <stdint.h>

// TopK activation: relu(x), keep top-k per row of 32768, zero the rest.
// One 1024-thread block per row; row lives in registers (32 elems/thread).
// Exact 3-round radix select (bits 31:21 / 20:10 / 9:0) on positive-float
// bit patterns; ties broken by lowest index (matches jax.lax.top_k).
// Perf structure: zero-store the whole output row immediately after load so
// the 1.07 GB write overlaps selection compute; scatter <=k kept values at
// the end. __launch_bounds__(1024,8) forces VGPR<=64 -> 2 blocks/CU.

#define NT   1024
#define NCOL 32768
#define VPT  8          // uint4 per thread -> 32 elems/thread
#define NB   2048       // histogram bins per round
#define REP  4          // histogram replicas (atomic contention relief)
#define LISTCAP 6144    // tie-index list capacity (aliases hist[1..3])

__global__ __launch_bounds__(NT, 8) void topk_select_kernel(
        const float* __restrict__ x, const int* __restrict__ kptr,
        float* __restrict__ out)
{
    __shared__ uint32_t hist[REP][NB];   // 32 KB; tielist aliases hist[1..]
    __shared__ int s_found, s_B, s_kth, s_neq, s_cnt, s_cut;

    const int tid  = threadIdx.x;
    const int lane = tid & 63;
    const int wave = tid >> 6;
    const size_t base = (size_t)blockIdx.x * NCOL;

    int k = kptr[0];
    if (k > NCOL) k = NCOL;

    const uint4* xv = (const uint4*)(x + base);
    uint4*       ov = (uint4*)(out + base);
    const uint4  z4 = make_uint4(0u, 0u, 0u, 0u);

    if (k <= 0) {   // uniform across block: write zeros and exit
        #pragma unroll
        for (int j = 0; j < VPT; ++j) ov[j * NT + tid] = z4;
        return;
    }

    // ---- load row, map to order-preserving keys (<=0 -> 0), zero out ----
    uint4 va[VPT];
    #pragma unroll
    for (int j = 0; j < VPT; ++j) va[j] = xv[j * NT + tid];
    #pragma unroll
    for (int j = 0; j < VPT; ++j) {
        uint32_t* p = (uint32_t*)&va[j];
        #pragma unroll
        for (int c = 0; c < 4; ++c) {
            uint32_t u = p[c];
            p[c] = ((int)u > 0) ? u : 0u;   // positive float bits are monotonic
        }
        ov[j * NT + tid] = z4;              // big write overlaps selection
    }

    // ---- 3-round radix select for the k-th largest key ----
    int kth = k;            // remaining rank within candidate set
    uint32_t prefix = 0u;   // selected high bits so far
    uint32_t thr = 0u;      // exact bits of k-th largest (mode 1)
    uint32_t keep_min = 0u; // mode 0: keep iff key >= keep_min
    int mode = 0;           // 0 = ge-threshold, 1 = exact thr + tie-break

    for (int round = 0; round < 3; ++round) {
        {   // clear histograms (vectorized, conflict-free)
            uint4* h4 = (uint4*)hist;
            #pragma unroll
            for (int i = 0; i < (REP * NB / 4) / NT; ++i)
                h4[i * NT + tid] = z4;
        }
        __syncthreads();

        {   // accumulate
            const int r = wave & (REP - 1);
            #pragma unroll
            for (int j = 0; j < VPT; ++j) {
                const uint32_t* p = (const uint32_t*)&va[j];
                #pragma unroll
                for (int c = 0; c < 4; ++c) {
                    uint32_t vv = p[c];
                    bool act; uint32_t bin;
                    if (round == 0)      { act = (vv != 0u);                           bin = vv >> 21; }
                    else if (round == 1) { act = (vv != 0u) && ((vv >> 21) == prefix); bin = (vv >> 10) & 0x7FFu; }
                    else                 { act = (vv != 0u) && ((vv >> 10) == prefix); bin = vv & 0x3FFu; }
                    if (act) atomicAdd(&hist[r][bin], 1u);
                }
            }
        }
        __syncthreads();

        // fold replicas into hist[0] (all threads, conflict-free)
        #pragma unroll
        for (int i = 0; i < NB / NT; ++i) {
            int b = i * NT + tid;
            hist[0][b] += hist[1][b] + hist[2][b] + hist[3][b];
        }
        __syncthreads();

        if (wave == 0) {
            // lane sums a 32-bin group (swizzled: 2 lanes/bank -> free)
            uint32_t s = 0;
            #pragma unroll 8
            for (int i = 0; i < 32; ++i)
                s += hist[0][lane * 32 + ((i + lane) & 31)];
            // inclusive suffix sum over 64 group totals
            uint32_t suf = s;
            #pragma unroll
            for (int d = 1; d < 64; d <<= 1) {
                uint32_t t2 = __shfl_down(suf, d);
                if (lane + d < 64) suf += t2;
            }
            uint32_t t1  = __shfl_down(suf, 1);
            uint32_t nxt = (lane == 63) ? 0u : t1;
            bool cond = (suf >= (uint32_t)kth) && (nxt < (uint32_t)kth);
            unsigned long long mask = __ballot(cond);
            if (mask == 0ull) {
                if (lane == 0) s_found = 0;   // fewer than kth positive values
            } else {
                int G = __ffsll(mask) - 1;
                uint32_t cntG = __shfl(nxt, G);   // count in groups above G
                uint32_t h2 = (lane < 32) ? hist[0][G * 32 + lane] : 0u;
                uint32_t suf2 = h2;
                #pragma unroll
                for (int d = 1; d < 64; d <<= 1) {
                    uint32_t t2 = __shfl_down(suf2, d);
                    if (lane + d < 64) suf2 += t2;
                }
                uint32_t t3   = __shfl_down(suf2, 1);
                uint32_t nxt2 = (lane == 63) ? 0u : t3;
                uint32_t ts   = cntG + suf2;
                uint32_t tsn  = cntG + nxt2;
                bool cond2 = (lane < 32) && (ts >= (uint32_t)kth) && (tsn < (uint32_t)kth);
                unsigned long long m2 = __ballot(cond2);
                int l = __ffsll(m2) - 1;
                uint32_t ngt  = __shfl(tsn, l);          // strictly-greater count
                uint32_t cbin = __shfl(suf2 - nxt2, l);  // count at selected bin
                if (lane == 0) {
                    s_found = 1;
                    s_B   = G * 32 + l;
                    s_kth = kth - (int)ngt;
                    s_neq = (int)cbin;
                }
            }
        }
        __syncthreads();

        // uniform decision from shared state
        if (!s_found) { keep_min = 1u; mode = 0; break; }   // keep all positives
        kth = s_kth;
        const int neq = s_neq;
        const uint32_t B = (uint32_t)s_B;
        if (round == 0) {
            if (neq == kth) { keep_min = B << 21; mode = 0; break; }
            prefix = B;
        } else if (round == 1) {
            if (neq == kth) { keep_min = ((prefix << 11) | B) << 10; mode = 0; break; }
            prefix = (prefix << 11) | B;
        } else {
            thr = (prefix << 10) | B;
            if (neq == kth) { keep_min = thr; mode = 0; }
            else            { mode = 1; }   // tie-break needed
        }
    }

    // ---- rare tie-break path: kth smallest index among key == thr ----
    int idx_cut = 0x7FFFFFFF;
    if (mode == 1) {                         // block-uniform
        uint32_t* tielist = &hist[1][0];     // hist free after rounds
        if (tid == 0) s_cnt = 0;
        __syncthreads();
        #pragma unroll
        for (int j = 0; j < VPT; ++j) {
            const uint32_t* p = (const uint32_t*)&va[j];
            #pragma unroll
            for (int c = 0; c < 4; ++c) {
                if (p[c] == thr) {
                    int slot = atomicAdd(&s_cnt, 1);
                    if (slot < LISTCAP)
                        tielist[slot] = (uint32_t)(j * 4096 + tid * 4 + c);
                }
            }
        }
        __syncthreads();
        if (tid == 0) {
            int n = s_cnt; if (n > LISTCAP) n = LISTCAP;
            for (int i = 1; i < n; ++i) {    // tiny insertion sort (rare path)
                uint32_t key = tielist[i]; int j2 = i - 1;
                while (j2 >= 0 && tielist[j2] > key) { tielist[j2 + 1] = tielist[j2]; --j2; }
                tielist[j2 + 1] = key;
            }
            s_cut = (kth >= 1 && kth <= n) ? (int)tielist[kth - 1] : 0x7FFFFFFF;
        }
        __syncthreads();
        idx_cut = s_cut;
    }

    // ---- scatter kept values (zero-stores already issued; order them) ----
    __threadfence_block();
    float* o = out + base;
    #pragma unroll
    for (int j = 0; j < VPT; ++j) {
        const uint32_t* p = (const uint32_t*)&va[j];
        #pragma unroll
        for (int c = 0; c < 4; ++c) {
            uint32_t vv = p[c];
            int idx = j * 4096 + tid * 4 + c;
            bool keep = (mode == 0) ? (vv >= keep_min && vv != 0u)
                                    : (vv > thr || (vv == thr && idx <= idx_cut));
            if (keep) o[idx] = __uint_as_float(vv);
        }
    }
}

extern "C" void kernel_launch(void* const* d_in, const int* in_sizes, int n_in,
                              void* d_out, int out_size, void* d_ws, size_t ws_size,
                              hipStream_t stream) {
    const float* x    = (const float*)d_in[0];
    const int*   kptr = (const int*)d_in[1];
    float*       out  = (float*)d_out;
    const int rows = in_sizes[0] / NCOL;
    topk_select_kernel<<<rows, NT, 0, stream>>>(x, kptr, out);
}